// Round 1
// baseline (155.335 us; speedup 1.0000x reference)
//
#include <hip/hip_runtime.h>

#define NUM_IDS 8192
#define D 512

// ---------------- kernels ----------------

__global__ __launch_bounds__(256) void k_zero(int* __restrict__ cnt, int* __restrict__ cursor) {
    int i = blockIdx.x * 256 + threadIdx.x;
    if (i < NUM_IDS) { cnt[i] = 0; cursor[i] = 0; }
}

__global__ __launch_bounds__(256) void k_count(const int* __restrict__ labels, int n,
                                               int* __restrict__ cnt) {
    int i = blockIdx.x * 256 + threadIdx.x;
    if (i < n) atomicAdd(&cnt[labels[i]], 1);
}

// One block, 1024 threads, 8 ids/thread. Dual exclusive scan over
// (present flag, count) -> rank[], offs[]; writes uniq output + num_unique.
__global__ __launch_bounds__(1024) void k_scan(const int* __restrict__ cnt,
                                               int* __restrict__ rank,
                                               int* __restrict__ offs,
                                               int* __restrict__ nuniq,
                                               float* __restrict__ uniq_out) {
    __shared__ int s_f[16], s_c[16];
    __shared__ int s_total;
    int t = threadIdx.x;
    int lane = t & 63, wave = t >> 6;
    int c[8], f[8];
    int fs = 0, cs = 0;
    int base = t * 8;
#pragma unroll
    for (int j = 0; j < 8; ++j) {
        c[j] = cnt[base + j];
        f[j] = (c[j] > 0) ? 1 : 0;
        fs += f[j]; cs += c[j];
    }
    // inclusive wave scan (wave = 64 lanes on CDNA)
    int fi = fs, ci = cs;
#pragma unroll
    for (int d = 1; d < 64; d <<= 1) {
        int fo = __shfl_up(fi, d, 64);
        int co = __shfl_up(ci, d, 64);
        if (lane >= d) { fi += fo; ci += co; }
    }
    if (lane == 63) { s_f[wave] = fi; s_c[wave] = ci; }
    __syncthreads();
    if (t == 0) {
        int af = 0, ac = 0;
#pragma unroll
        for (int w = 0; w < 16; ++w) {
            int tf = s_f[w], tc = s_c[w];
            s_f[w] = af; s_c[w] = ac;   // exclusive wave offsets
            af += tf; ac += tc;
        }
        s_total = af;
        nuniq[0] = af;
    }
    __syncthreads();
    int fexcl = (fi - fs) + s_f[wave];
    int cexcl = (ci - cs) + s_c[wave];
    int total = s_total;
#pragma unroll
    for (int j = 0; j < 8; ++j) {
        int id = base + j;
        rank[id] = fexcl;
        offs[id] = cexcl;
        if (f[j]) uniq_out[fexcl] = (float)id;   // sorted unique ids
        if (id >= total) uniq_out[id] = -1.0f;   // jnp.unique fill_value
        fexcl += f[j];
        cexcl += c[j];
    }
}

__global__ __launch_bounds__(256) void k_fill(const int* __restrict__ labels, int n,
                                              const int* __restrict__ offs,
                                              int* __restrict__ cursor,
                                              int* __restrict__ rowidx) {
    int i = blockIdx.x * 256 + threadIdx.x;
    if (i < n) {
        int id = labels[i];
        int p = atomicAdd(&cursor[id], 1);
        rowidx[offs[id] + p] = i;
    }
}

// One block per id; 128 threads, thread t owns float4 at column 4t.
// Each row read = contiguous 2 KB across the block (fully coalesced).
__global__ __launch_bounds__(128) void k_agg(const float* __restrict__ emb,
                                             const int* __restrict__ cnt,
                                             const int* __restrict__ rank,
                                             const int* __restrict__ offs,
                                             const int* __restrict__ rowidx,
                                             const int* __restrict__ nuniq,
                                             float* __restrict__ agg) {
    int id = blockIdx.x;
    int t = threadIdx.x;
    int n = cnt[id];
    if (n == 0) {
        // absent id -> one of the tail rows; segment_sum leaves it 0, /max(1)=0
        int outrow = nuniq[0] + (id - rank[id]);
        float4 z = {0.f, 0.f, 0.f, 0.f};
        reinterpret_cast<float4*>(agg + (size_t)outrow * D)[t] = z;
        return;
    }
    int off = offs[id];
    float ax0 = 0.f, ay0 = 0.f, az0 = 0.f, aw0 = 0.f;
    float ax1 = 0.f, ay1 = 0.f, az1 = 0.f, aw1 = 0.f;
    int r = 0;
    for (; r + 2 <= n; r += 2) {
        int r0 = rowidx[off + r];
        int r1 = rowidx[off + r + 1];
        float4 v0 = reinterpret_cast<const float4*>(emb + (size_t)r0 * D)[t];
        float4 v1 = reinterpret_cast<const float4*>(emb + (size_t)r1 * D)[t];
        ax0 += v0.x; ay0 += v0.y; az0 += v0.z; aw0 += v0.w;
        ax1 += v1.x; ay1 += v1.y; az1 += v1.z; aw1 += v1.w;
    }
    if (r < n) {
        int r0 = rowidx[off + r];
        float4 v0 = reinterpret_cast<const float4*>(emb + (size_t)r0 * D)[t];
        ax0 += v0.x; ay0 += v0.y; az0 += v0.z; aw0 += v0.w;
    }
    float inv = 1.0f / (float)n;
    float4 o;
    o.x = (ax0 + ax1) * inv;
    o.y = (ay0 + ay1) * inv;
    o.z = (az0 + az1) * inv;
    o.w = (aw0 + aw1) * inv;
    reinterpret_cast<float4*>(agg + (size_t)rank[id] * D)[t] = o;
}

// ---------------- launch ----------------

extern "C" void kernel_launch(void* const* d_in, const int* in_sizes, int n_in,
                              void* d_out, int out_size, void* d_ws, size_t ws_size,
                              hipStream_t stream) {
    const float* emb   = (const float*)d_in[0];
    const int* labels  = (const int*)d_in[1];
    const int n = in_sizes[1];

    float* agg  = (float*)d_out;                       // [NUM_IDS, D]
    float* uniq = agg + (size_t)NUM_IDS * D;           // [NUM_IDS]

    int* ws     = (int*)d_ws;
    int* cnt    = ws;                                  // [NUM_IDS]
    int* rank   = ws + NUM_IDS;                        // [NUM_IDS]
    int* offs   = ws + 2 * NUM_IDS;                    // [NUM_IDS]
    int* cursor = ws + 3 * NUM_IDS;                    // [NUM_IDS]
    int* nuniq  = ws + 4 * NUM_IDS;                    // [1]
    int* rowidx = ws + 4 * NUM_IDS + 64;               // [n]

    k_zero <<<NUM_IDS / 256, 256, 0, stream>>>(cnt, cursor);
    k_count<<<(n + 255) / 256, 256, 0, stream>>>(labels, n, cnt);
    k_scan <<<1, 1024, 0, stream>>>(cnt, rank, offs, nuniq, uniq);
    k_fill <<<(n + 255) / 256, 256, 0, stream>>>(labels, n, offs, cursor, rowidx);
    k_agg  <<<NUM_IDS, 128, 0, stream>>>(emb, cnt, rank, offs, rowidx, nuniq, agg);
}